// Round 1
// baseline (323.348 us; speedup 1.0000x reference)
//
#include <hip/hip_runtime.h>
#include <stdint.h>

typedef __bf16 bf16x8 __attribute__((ext_vector_type(8)));
typedef float f32x4 __attribute__((ext_vector_type(4)));

#define AS1 __attribute__((address_space(1)))
#define AS3 __attribute__((address_space(3)))

__device__ __forceinline__ unsigned short f2bf(float f) {
    unsigned int u = __float_as_uint(f);
    u += 0x7FFFu + ((u >> 16) & 1u);   // round-to-nearest-even (inputs are finite)
    return (unsigned short)(u >> 16);
}

// global -> LDS direct DMA, 16B per lane. LDS dest must be wave-uniform base.
// AS1 cast via inttoptr (identity for global); AS3 via 32-bit truncation
// (LDS aperture is 4GB-aligned, low 32 bits are the LDS offset).
__device__ __forceinline__ void gload16(const void* g, void* l) {
    __builtin_amdgcn_global_load_lds(
        (AS1 void*)(uintptr_t)g,
        (AS3 void*)(unsigned int)(uintptr_t)l,
        16, 0, 0);
}

// ---------------- kernel 1: Wp/Wc -> bf16, zero score accumulator ----------------
__global__ __launch_bounds__(256) void k_convert_w(
    const float* __restrict__ Wp, const float* __restrict__ Wc,
    unsigned short* __restrict__ Wp_bf, unsigned short* __restrict__ Wc_bf,
    float* __restrict__ score_acc)
{
    int i = blockIdx.x * 256 + threadIdx.x;          // 0 .. 262143, x4 floats = 1M each
    if (i == 0) score_acc[0] = 0.0f;
    float4 a = reinterpret_cast<const float4*>(Wp)[i];
    float4 b = reinterpret_cast<const float4*>(Wc)[i];
    ushort4 ra, rb;
    ra.x = f2bf(a.x); ra.y = f2bf(a.y); ra.z = f2bf(a.z); ra.w = f2bf(a.w);
    rb.x = f2bf(b.x); rb.y = f2bf(b.y); rb.z = f2bf(b.z); rb.w = f2bf(b.w);
    reinterpret_cast<ushort4*>(Wp_bf)[i] = ra;
    reinterpret_cast<ushort4*>(Wc_bf)[i] = rb;
}

// ---------------- kernel 2: x -> bf16 copy + accept gate ----------------
__global__ __launch_bounds__(256) void k_gate_convert(
    const float* __restrict__ x, const float* __restrict__ Wg, const float* __restrict__ bg,
    unsigned short* __restrict__ x_bf, float* __restrict__ gate)
{
    const int s = blockIdx.x;            // token row
    const int t = threadIdx.x;           // 256 threads x 4 floats = 1024
    const size_t base = (size_t)s * 1024;
    float4 v = reinterpret_cast<const float4*>(x + base)[t];
    float4 w = reinterpret_cast<const float4*>(Wg)[t];
    ushort4 r;
    r.x = f2bf(v.x); r.y = f2bf(v.y); r.z = f2bf(v.z); r.w = f2bf(v.w);
    reinterpret_cast<ushort4*>(x_bf + base)[t] = r;
    float p = v.x*w.x + v.y*w.y + v.z*w.z + v.w*w.w;
    #pragma unroll
    for (int off = 32; off > 0; off >>= 1) p += __shfl_down(p, off);
    __shared__ float sm[4];
    if ((t & 63) == 0) sm[t >> 6] = p;
    __syncthreads();
    if (t == 0) {
        float z = sm[0] + sm[1] + sm[2] + sm[3] + bg[0];
        gate[s] = 1.0f / (1.0f + expf(-z));
    }
}

// ---------------- GEMM: C[M,1024] = A[M,1024](bf16) @ Bw[1024,1024]^T(bf16) + bias ----
// 128x128 tile, BK=64, 4 waves (2x2), mfma_f32_16x16x32_bf16, m97 2-barrier loop.
// LDS XOR-swizzle (byte ^= (row&7)<<4) applied on BOTH the global source address
// (global_load_lds writes linearly) and the ds_read address (rule #21).
// CHUNK_EPI: fused per-16-row chunk means (each 16x16 fragment = one whole chunk).
template<bool CHUNK_EPI>
__global__ __launch_bounds__(256) void k_gemm(
    const unsigned short* __restrict__ A,
    const unsigned short* __restrict__ Bw,
    const float* __restrict__ bias,
    float* __restrict__ C,
    unsigned short* __restrict__ cmean)
{
    __shared__ alignas(16) unsigned char lds[32768];
    unsigned char* ldsA = lds;
    unsigned char* ldsB = lds + 16384;

    const int tid  = threadIdx.x;
    const int lane = tid & 63;
    const int wid  = tid >> 6;
    const int wm   = wid >> 1;
    const int wn   = wid & 1;
    const int bm   = blockIdx.x;
    const int bn   = blockIdx.y;

    // staging: wave covers 32 rows (4 issues x 8 rows); lane -> (row l>>3, 16B chunk l&7)
    const int l8 = lane >> 3;
    const int kColOff = (((lane & 7) ^ l8) << 3);          // pre-swizzled source k-offset (elems)
    const size_t aRow = (size_t)(bm * 128 + wid * 32 + l8) * 1024;
    const size_t bRow = (size_t)(bn * 128 + wid * 32 + l8) * 1024;
    const int ldsWave = wid * 32 * 128;                     // wave staging byte offset

    const int l15 = lane & 15;
    const int lq  = lane >> 4;
    const int rswz = (lane & 7) << 4;                       // read-side swizzle ((row&7)<<4 == (lane&7)<<4)

    f32x4 acc[4][4];
    #pragma unroll
    for (int i = 0; i < 4; ++i)
        #pragma unroll
        for (int j = 0; j < 4; ++j)
            acc[i][j] = f32x4{0.f, 0.f, 0.f, 0.f};

    for (int k0 = 0; k0 < 1024; k0 += 64) {
        __syncthreads();                                    // prev reads done before overwrite
        #pragma unroll
        for (int i = 0; i < 4; ++i)
            gload16(A + aRow + (size_t)(i * 8) * 1024 + (k0 + kColOff),
                    ldsA + ldsWave + i * 1024);
        #pragma unroll
        for (int i = 0; i < 4; ++i)
            gload16(Bw + bRow + (size_t)(i * 8) * 1024 + (k0 + kColOff),
                    ldsB + ldsWave + i * 1024);
        __syncthreads();                                    // compiler drains vmcnt(0) before barrier

        #pragma unroll
        for (int kj = 0; kj < 2; ++kj) {
            const int rboff = ((kj * 64 + lq * 16) ^ rswz);
            bf16x8 af[4], bfr[4];
            #pragma unroll
            for (int mi = 0; mi < 4; ++mi)
                af[mi] = *reinterpret_cast<const bf16x8*>(ldsA + (wm*64 + mi*16 + l15) * 128 + rboff);
            #pragma unroll
            for (int ni = 0; ni < 4; ++ni)
                bfr[ni] = *reinterpret_cast<const bf16x8*>(ldsB + (wn*64 + ni*16 + l15) * 128 + rboff);
            #pragma unroll
            for (int mi = 0; mi < 4; ++mi)
                #pragma unroll
                for (int ni = 0; ni < 4; ++ni)
                    acc[mi][ni] = __builtin_amdgcn_mfma_f32_16x16x32_bf16(
                        af[mi], bfr[ni], acc[mi][ni], 0, 0, 0);
        }
    }

    // epilogue: bias add, C store (scalar dwords: C base may be 4B-aligned only),
    // fused chunk means. D layout: col = lane&15, row = 4*(lane>>4)+reg.
    const int colBase = bn * 128 + wn * 64;
    const int rowBase = bm * 128 + wm * 64;
    #pragma unroll
    for (int ni = 0; ni < 4; ++ni) {
        const int col = colBase + ni * 16 + l15;
        const float bv = bias[col];
        #pragma unroll
        for (int mi = 0; mi < 4; ++mi) {
            f32x4 v = acc[mi][ni];
            v[0] += bv; v[1] += bv; v[2] += bv; v[3] += bv;
            const int r0 = rowBase + mi * 16 + lq * 4;
            C[(size_t)(r0 + 0) * 1024 + col] = v[0];
            C[(size_t)(r0 + 1) * 1024 + col] = v[1];
            C[(size_t)(r0 + 2) * 1024 + col] = v[2];
            C[(size_t)(r0 + 3) * 1024 + col] = v[3];
            if constexpr (CHUNK_EPI) {
                float sgroup = v[0] + v[1] + v[2] + v[3];   // 4 rows of this lane-quad
                sgroup += __shfl_xor(sgroup, 16);           // combine 4 lane-quads -> 16 rows
                sgroup += __shfl_xor(sgroup, 32);
                if (lq == 0) {
                    const int chunk = bm * 8 + wm * 4 + mi; // fragment == one whole chunk
                    cmean[(size_t)chunk * 1024 + col] = f2bf(sgroup * 0.0625f);
                }
            }
        }
    }
}

// ---------------- kernel 4: feedback + cosine similarity + score accumulate ----------
__global__ __launch_bounds__(256) void k_epilogue(
    const float* __restrict__ tp, const float* __restrict__ cons,
    const float* __restrict__ gate, float* __restrict__ fb,
    float* __restrict__ score_acc)
{
    const int s = blockIdx.x;
    const int t = threadIdx.x;
    const size_t rb = (size_t)s * 1024;
    float4 cv = reinterpret_cast<const float4*>(cons + (size_t)(s >> 4) * 1024)[t];
    const float g = gate[s];
    float4 f;
    f.x = g * cv.x; f.y = g * cv.y; f.z = g * cv.z; f.w = g * cv.w;
    reinterpret_cast<float4*>(fb + rb)[t] = f;
    const float* tr = tp + rb + t * 4;                     // tp base is odd -> scalar loads
    float t0 = tr[0], t1 = tr[1], t2 = tr[2], t3 = tr[3];
    float num = t0*cv.x + t1*cv.y + t2*cv.z + t3*cv.w;
    float ntp = t0*t0 + t1*t1 + t2*t2 + t3*t3;
    float ncs = cv.x*cv.x + cv.y*cv.y + cv.z*cv.z + cv.w*cv.w;
    #pragma unroll
    for (int off = 32; off > 0; off >>= 1) {
        num += __shfl_down(num, off);
        ntp += __shfl_down(ntp, off);
        ncs += __shfl_down(ncs, off);
    }
    __shared__ float smn[4], smt[4], smc[4];
    const int w = t >> 6;
    if ((t & 63) == 0) { smn[w] = num; smt[w] = ntp; smc[w] = ncs; }
    __syncthreads();
    if (t == 0) {
        num = smn[0] + smn[1] + smn[2] + smn[3];
        ntp = smt[0] + smt[1] + smt[2] + smt[3];
        ncs = smc[0] + smc[1] + smc[2] + smc[3];
        float den = fmaxf(sqrtf(ntp), 1e-8f) * fmaxf(sqrtf(ncs), 1e-8f);
        atomicAdd(score_acc, num / den);
    }
}

__global__ void k_finalize(const float* __restrict__ acc, float* __restrict__ out) {
    out[0] = acc[0] * (1.0f / 16384.0f);
}

extern "C" void kernel_launch(void* const* d_in, const int* in_sizes, int n_in,
                              void* d_out, int out_size, void* d_ws, size_t ws_size,
                              hipStream_t stream)
{
    (void)in_sizes; (void)n_in; (void)out_size; (void)ws_size;
    const float* x  = (const float*)d_in[0];
    const float* Wp = (const float*)d_in[1];
    const float* bp = (const float*)d_in[2];
    const float* Wc = (const float*)d_in[3];
    const float* bc = (const float*)d_in[4];
    const float* Wg = (const float*)d_in[5];
    const float* bg = (const float*)d_in[6];
    float* out = (float*)d_out;

    unsigned char* ws = (unsigned char*)d_ws;
    unsigned short* x_bf  = (unsigned short*)(ws);               // 32 MiB
    unsigned short* Wp_bf = (unsigned short*)(ws + 33554432);    // 2 MiB
    unsigned short* Wc_bf = (unsigned short*)(ws + 35651584);    // 2 MiB
    unsigned short* cmean = (unsigned short*)(ws + 37748736);    // 2 MiB
    float* gate      = (float*)(ws + 39845888);                  // 64 KiB
    float* score_acc = (float*)(ws + 39911424);                  // 4 B

    // output regions (floats): pc | feedback | score | token_proposals
    float* pc = out;                  // [4*256,1024]
    float* fb = out + 1048576;        // [4*4096,1024]
    float* sc = out + 17825792;       // [1]
    float* tp = out + 17825793;       // [4*4096,1024]  (odd offset: scalar access only)

    k_convert_w<<<1024, 256, 0, stream>>>(Wp, Wc, Wp_bf, Wc_bf, score_acc);
    k_gate_convert<<<16384, 256, 0, stream>>>(x, Wg, bg, x_bf, gate);
    k_gemm<true><<<dim3(128, 8), 256, 0, stream>>>(x_bf, Wp_bf, bp, tp, cmean);
    k_gemm<false><<<dim3(8, 8), 256, 0, stream>>>(cmean, Wc_bf, bc, pc, (unsigned short*)nullptr);
    k_epilogue<<<16384, 256, 0, stream>>>(tp, pc, gate, fb, score_acc);
    k_finalize<<<1, 1, 0, stream>>>(score_acc, sc);
}

// Round 2
// 137.308 us; speedup vs baseline: 2.3549x; 2.3549x over previous
//
#include <hip/hip_runtime.h>
#include <stdint.h>

typedef __bf16 bf16x8 __attribute__((ext_vector_type(8)));
typedef float f32x4 __attribute__((ext_vector_type(4)));

#define AS1 __attribute__((address_space(1)))
#define AS3 __attribute__((address_space(3)))

__device__ __forceinline__ unsigned short f2bf(float f) {
    unsigned int u = __float_as_uint(f);
    u += 0x7FFFu + ((u >> 16) & 1u);   // round-to-nearest-even (inputs are finite)
    return (unsigned short)(u >> 16);
}

__device__ __forceinline__ float wave_sum(float v) {
    #pragma unroll
    for (int off = 1; off < 64; off <<= 1) v += __shfl_xor(v, off);
    return v;
}

// global -> LDS direct DMA, 16B per lane. LDS dest must be wave-uniform base.
__device__ __forceinline__ void gload16(const void* g, void* l) {
    __builtin_amdgcn_global_load_lds(
        (AS1 void*)(uintptr_t)g,
        (AS3 void*)(unsigned int)(uintptr_t)l,
        16, 0, 0);
}

// ---------------- kernel 1: Wp/Wc -> bf16, zero score accumulator ----------------
__global__ __launch_bounds__(256) void k_convert_w(
    const float* __restrict__ Wp, const float* __restrict__ Wc,
    unsigned short* __restrict__ Wp_bf, unsigned short* __restrict__ Wc_bf,
    float* __restrict__ score_acc)
{
    int i = blockIdx.x * 256 + threadIdx.x;          // 0 .. 262143, x4 floats = 1M each
    if (i == 0) score_acc[0] = 0.0f;
    float4 a = reinterpret_cast<const float4*>(Wp)[i];
    float4 b = reinterpret_cast<const float4*>(Wc)[i];
    ushort4 ra, rb;
    ra.x = f2bf(a.x); ra.y = f2bf(a.y); ra.z = f2bf(a.z); ra.w = f2bf(a.w);
    rb.x = f2bf(b.x); rb.y = f2bf(b.y); rb.z = f2bf(b.z); rb.w = f2bf(b.w);
    reinterpret_cast<ushort4*>(Wp_bf)[i] = ra;
    reinterpret_cast<ushort4*>(Wc_bf)[i] = rb;
}

// ---------------- kernel 2: x -> bf16 copy + accept gate ----------------
__global__ __launch_bounds__(256) void k_gate_convert(
    const float* __restrict__ x, const float* __restrict__ Wg, const float* __restrict__ bg,
    unsigned short* __restrict__ x_bf, float* __restrict__ gate)
{
    const int s = blockIdx.x;            // token row
    const int t = threadIdx.x;           // 256 threads x 4 floats = 1024
    const size_t base = (size_t)s * 1024;
    float4 v = reinterpret_cast<const float4*>(x + base)[t];
    float4 w = reinterpret_cast<const float4*>(Wg)[t];
    ushort4 r;
    r.x = f2bf(v.x); r.y = f2bf(v.y); r.z = f2bf(v.z); r.w = f2bf(v.w);
    reinterpret_cast<ushort4*>(x_bf + base)[t] = r;
    float p = v.x*w.x + v.y*w.y + v.z*w.z + v.w*w.w;
    #pragma unroll
    for (int off = 32; off > 0; off >>= 1) p += __shfl_down(p, off);
    __shared__ float sm[4];
    if ((t & 63) == 0) sm[t >> 6] = p;
    __syncthreads();
    if (t == 0) {
        float z = sm[0] + sm[1] + sm[2] + sm[3] + bg[0];
        gate[s] = 1.0f / (1.0f + expf(-z));
    }
}

// ---------------- GEMM: C[M,1024] = A[M,1024](bf16) @ Bw[1024,1024]^T(bf16) + bias ----
// 128x128 tile, BK=64, 4 waves (2x2), mfma_f32_16x16x32_bf16, m97 2-barrier loop.
// LDS XOR-swizzle (byte ^= (row&7)<<4) applied on BOTH the global source address
// (global_load_lds writes linearly) and the ds_read address (rule #21).
// CHUNK_EPI: fused per-16-row chunk means (each 16x16 fragment = one whole chunk).
template<bool CHUNK_EPI>
__global__ __launch_bounds__(256) void k_gemm(
    const unsigned short* __restrict__ A,
    const unsigned short* __restrict__ Bw,
    const float* __restrict__ bias,
    float* __restrict__ C,
    unsigned short* __restrict__ cmean)
{
    __shared__ alignas(16) unsigned char lds[32768];
    unsigned char* ldsA = lds;
    unsigned char* ldsB = lds + 16384;

    const int tid  = threadIdx.x;
    const int lane = tid & 63;
    const int wid  = tid >> 6;
    const int wm   = wid >> 1;
    const int wn   = wid & 1;
    const int bm   = blockIdx.x;
    const int bn   = blockIdx.y;

    // staging: wave covers 32 rows (4 issues x 8 rows); lane -> (row l>>3, 16B chunk l&7)
    const int l8 = lane >> 3;
    const int kColOff = (((lane & 7) ^ l8) << 3);          // pre-swizzled source k-offset (elems)
    const size_t aRow = (size_t)(bm * 128 + wid * 32 + l8) * 1024;
    const size_t bRow = (size_t)(bn * 128 + wid * 32 + l8) * 1024;
    const int ldsWave = wid * 32 * 128;                     // wave staging byte offset

    const int l15 = lane & 15;
    const int lq  = lane >> 4;
    const int rswz = (lane & 7) << 4;                       // read-side swizzle ((row&7)<<4 == (lane&7)<<4)

    f32x4 acc[4][4];
    #pragma unroll
    for (int i = 0; i < 4; ++i)
        #pragma unroll
        for (int j = 0; j < 4; ++j)
            acc[i][j] = f32x4{0.f, 0.f, 0.f, 0.f};

    for (int k0 = 0; k0 < 1024; k0 += 64) {
        __syncthreads();                                    // prev reads done before overwrite
        #pragma unroll
        for (int i = 0; i < 4; ++i)
            gload16(A + aRow + (size_t)(i * 8) * 1024 + (k0 + kColOff),
                    ldsA + ldsWave + i * 1024);
        #pragma unroll
        for (int i = 0; i < 4; ++i)
            gload16(Bw + bRow + (size_t)(i * 8) * 1024 + (k0 + kColOff),
                    ldsB + ldsWave + i * 1024);
        __syncthreads();                                    // compiler drains vmcnt(0) before barrier

        #pragma unroll
        for (int kj = 0; kj < 2; ++kj) {
            const int rboff = ((kj * 64 + lq * 16) ^ rswz);
            bf16x8 af[4], bfr[4];
            #pragma unroll
            for (int mi = 0; mi < 4; ++mi)
                af[mi] = *reinterpret_cast<const bf16x8*>(ldsA + (wm*64 + mi*16 + l15) * 128 + rboff);
            #pragma unroll
            for (int ni = 0; ni < 4; ++ni)
                bfr[ni] = *reinterpret_cast<const bf16x8*>(ldsB + (wn*64 + ni*16 + l15) * 128 + rboff);
            #pragma unroll
            for (int mi = 0; mi < 4; ++mi)
                #pragma unroll
                for (int ni = 0; ni < 4; ++ni)
                    acc[mi][ni] = __builtin_amdgcn_mfma_f32_16x16x32_bf16(
                        af[mi], bfr[ni], acc[mi][ni], 0, 0, 0);
        }
    }

    // epilogue: bias add, C store (scalar dwords: C base may be 4B-aligned only),
    // fused chunk means. D layout: col = lane&15, row = 4*(lane>>4)+reg.
    const int colBase = bn * 128 + wn * 64;
    const int rowBase = bm * 128 + wm * 64;
    #pragma unroll
    for (int ni = 0; ni < 4; ++ni) {
        const int col = colBase + ni * 16 + l15;
        const float bv = bias[col];
        #pragma unroll
        for (int mi = 0; mi < 4; ++mi) {
            f32x4 v = acc[mi][ni];
            v[0] += bv; v[1] += bv; v[2] += bv; v[3] += bv;
            const int r0 = rowBase + mi * 16 + lq * 4;
            C[(size_t)(r0 + 0) * 1024 + col] = v[0];
            C[(size_t)(r0 + 1) * 1024 + col] = v[1];
            C[(size_t)(r0 + 2) * 1024 + col] = v[2];
            C[(size_t)(r0 + 3) * 1024 + col] = v[3];
            if constexpr (CHUNK_EPI) {
                float sgroup = v[0] + v[1] + v[2] + v[3];   // 4 rows of this lane-quad
                sgroup += __shfl_xor(sgroup, 16);           // combine 4 lane-quads -> 16 rows
                sgroup += __shfl_xor(sgroup, 32);
                if (lq == 0) {
                    const int chunk = bm * 8 + wm * 4 + mi; // fragment == one whole chunk
                    cmean[(size_t)chunk * 1024 + col] = f2bf(sgroup * 0.0625f);
                }
            }
        }
    }
}

// ---------------- kernel 4: feedback + cosine similarity + score accumulate ----------
// One block per chunk (1024 blocks). cons row loaded ONCE into registers and reused
// for all 16 tokens; ncs reduced once per wave; per-token reductions are wave-only
// shfl_xor butterflies; ONE atomicAdd per block (1024 total, was 16384).
__global__ __launch_bounds__(256) void k_epilogue(
    const float* __restrict__ tp, const float* __restrict__ cons,
    const float* __restrict__ gate, float* __restrict__ fb,
    float* __restrict__ score_acc)
{
    const int chunk = blockIdx.x;           // 0..1023
    const int lane  = threadIdx.x & 63;
    const int w     = threadIdx.x >> 6;     // wave 0..3, each handles 4 tokens
    const size_t cbase = (size_t)chunk * 1024 + lane * 16;

    float cvl[16];
    #pragma unroll
    for (int q = 0; q < 4; ++q) {
        float4 cq = reinterpret_cast<const float4*>(cons + cbase)[q];
        cvl[q*4+0] = cq.x; cvl[q*4+1] = cq.y; cvl[q*4+2] = cq.z; cvl[q*4+3] = cq.w;
    }
    float ncs = 0.f;
    #pragma unroll
    for (int j = 0; j < 16; ++j) ncs += cvl[j] * cvl[j];
    ncs = wave_sum(ncs);                    // chunk-invariant: once per wave
    const float cnorm = fmaxf(sqrtf(ncs), 1e-8f);

    float local = 0.f;
    #pragma unroll
    for (int i = 0; i < 4; ++i) {
        const int s = chunk * 16 + w * 4 + i;
        const float g = gate[s];
        const float* tr = tp + (size_t)s * 1024 + lane * 16;   // odd base -> scalar dword loads
        float* fr = fb + (size_t)s * 1024 + lane * 16;         // 16B-aligned -> float4 stores
        float num = 0.f, ntp = 0.f;
        #pragma unroll
        for (int j = 0; j < 16; ++j) {
            const float tv = tr[j];
            num += tv * cvl[j];
            ntp += tv * tv;
        }
        #pragma unroll
        for (int q = 0; q < 4; ++q) {
            float4 fo;
            fo.x = g * cvl[q*4+0]; fo.y = g * cvl[q*4+1];
            fo.z = g * cvl[q*4+2]; fo.w = g * cvl[q*4+3];
            reinterpret_cast<float4*>(fr)[q] = fo;
        }
        num = wave_sum(num);
        ntp = wave_sum(ntp);
        if (lane == 0) local += num / (fmaxf(sqrtf(ntp), 1e-8f) * cnorm);
    }

    __shared__ float sm[4];
    if (lane == 0) sm[w] = local;
    __syncthreads();
    if (threadIdx.x == 0)
        atomicAdd(score_acc, sm[0] + sm[1] + sm[2] + sm[3]);
}

__global__ void k_finalize(const float* __restrict__ acc, float* __restrict__ out) {
    out[0] = acc[0] * (1.0f / 16384.0f);
}

extern "C" void kernel_launch(void* const* d_in, const int* in_sizes, int n_in,
                              void* d_out, int out_size, void* d_ws, size_t ws_size,
                              hipStream_t stream)
{
    (void)in_sizes; (void)n_in; (void)out_size; (void)ws_size;
    const float* x  = (const float*)d_in[0];
    const float* Wp = (const float*)d_in[1];
    const float* bp = (const float*)d_in[2];
    const float* Wc = (const float*)d_in[3];
    const float* bc = (const float*)d_in[4];
    const float* Wg = (const float*)d_in[5];
    const float* bg = (const float*)d_in[6];
    float* out = (float*)d_out;

    unsigned char* ws = (unsigned char*)d_ws;
    unsigned short* x_bf  = (unsigned short*)(ws);               // 32 MiB
    unsigned short* Wp_bf = (unsigned short*)(ws + 33554432);    // 2 MiB
    unsigned short* Wc_bf = (unsigned short*)(ws + 35651584);    // 2 MiB
    unsigned short* cmean = (unsigned short*)(ws + 37748736);    // 2 MiB
    float* gate      = (float*)(ws + 39845888);                  // 64 KiB
    float* score_acc = (float*)(ws + 39911424);                  // 4 B

    // output regions (floats): pc | feedback | score | token_proposals
    float* pc = out;                  // [4*256,1024]
    float* fb = out + 1048576;        // [4*4096,1024]
    float* sc = out + 17825792;       // [1]
    float* tp = out + 17825793;       // [4*4096,1024]  (odd offset: scalar access only)

    k_convert_w<<<1024, 256, 0, stream>>>(Wp, Wc, Wp_bf, Wc_bf, score_acc);
    k_gate_convert<<<16384, 256, 0, stream>>>(x, Wg, bg, x_bf, gate);
    k_gemm<true><<<dim3(128, 8), 256, 0, stream>>>(x_bf, Wp_bf, bp, tp, cmean);
    k_gemm<false><<<dim3(8, 8), 256, 0, stream>>>(cmean, Wc_bf, bc, pc, (unsigned short*)nullptr);
    k_epilogue<<<1024, 256, 0, stream>>>(tp, pc, gate, fb, score_acc);
    k_finalize<<<1, 1, 0, stream>>>(score_acc, sc);
}